// Round 1
// baseline (26.762 us; speedup 1.0000x reference)
//
#include <hip/hip_runtime.h>
#include <hip/hip_bf16.h>

// y = relu(x @ W1 + b1) @ W2 + b2
// x:[B,64] f32, W1:[64,128], b1:[128], W2:[128,32], b2:[32], y:[B,32] f32
#define B_ROWS 262144
#define N_TILES (B_ROWS / 16)

typedef short short8 __attribute__((ext_vector_type(8)));
typedef float f32x4 __attribute__((ext_vector_type(4)));
typedef float f32x4u __attribute__((ext_vector_type(4)));

__device__ inline short f2bf(float f) {
    __hip_bfloat16 h = __float2bfloat16(f);
    return __builtin_bit_cast(short, h);
}

__global__ __launch_bounds__(256, 2) void livenet_mlp(
    const float* __restrict__ x, const float* __restrict__ W1,
    const float* __restrict__ b1, const float* __restrict__ W2,
    const float* __restrict__ b2, float* __restrict__ y) {
    // per-wave h staging buffer: 16 rows x 128 cols bf16 = 2048 shorts (4 KB)
    __shared__ short hbuf[4 * 2048];

    const int tid  = threadIdx.x;
    const int wid  = tid >> 6;
    const int lane = tid & 63;
    const int g    = lane >> 4;   // k-group 0..3
    const int q    = lane & 15;   // row/col within tile
    short* hb = hbuf + wid * 2048;

    // ---- load weight fragments once per wave (L2-resident, amortized) ----
    // GEMM1 B-frags: w1f[ks][n], element j = bf16(W1[(ks*32+g*8+j)*128 + n*16+q])
    short8 w1f[2][8];
#pragma unroll
    for (int ks = 0; ks < 2; ++ks)
#pragma unroll
        for (int n = 0; n < 8; ++n) {
            short8 v;
#pragma unroll
            for (int j = 0; j < 8; ++j)
                v[j] = f2bf(W1[(ks * 32 + g * 8 + j) * 128 + n * 16 + q]);
            w1f[ks][n] = v;
        }
    // GEMM2 B-frags: w2f[ks][n]
    short8 w2f[4][2];
#pragma unroll
    for (int ks = 0; ks < 4; ++ks)
#pragma unroll
        for (int n = 0; n < 2; ++n) {
            short8 v;
#pragma unroll
            for (int j = 0; j < 8; ++j)
                v[j] = f2bf(W2[(ks * 32 + g * 8 + j) * 32 + n * 16 + q]);
            w2f[ks][n] = v;
        }
    float b1v[8], b2v[2];
#pragma unroll
    for (int n = 0; n < 8; ++n) b1v[n] = b1[n * 16 + q];
#pragma unroll
    for (int n = 0; n < 2; ++n) b2v[n] = b2[n * 16 + q];

    const int gwave    = blockIdx.x * 4 + wid;
    const int n_gwaves = gridDim.x * 4;

    for (int tile = gwave; tile < N_TILES; tile += n_gwaves) {
        const int row0 = tile * 16;

        // ---- load x A-fragments: row q, k = ks*32 + g*8 + j (f32 -> bf16) ----
        short8 a[2];
#pragma unroll
        for (int ks = 0; ks < 2; ++ks) {
            const f32x4u* p = (const f32x4u*)(x + (size_t)(row0 + q) * 64 + ks * 32 + g * 8);
            f32x4 lo = p[0];
            f32x4 hi = p[1];
            short8 v;
            v[0] = f2bf(lo[0]); v[1] = f2bf(lo[1]); v[2] = f2bf(lo[2]); v[3] = f2bf(lo[3]);
            v[4] = f2bf(hi[0]); v[5] = f2bf(hi[1]); v[6] = f2bf(hi[2]); v[7] = f2bf(hi[3]);
            a[ks] = v;
        }

        // ---- GEMM1: h[16][128] = x @ W1 + b1 ----
        f32x4 acc1[8];
#pragma unroll
        for (int n = 0; n < 8; ++n)
            acc1[n] = (f32x4){b1v[n], b1v[n], b1v[n], b1v[n]};
#pragma unroll
        for (int ks = 0; ks < 2; ++ks)
#pragma unroll
            for (int n = 0; n < 8; ++n)
                acc1[n] = __builtin_amdgcn_mfma_f32_16x16x32_bf16(a[ks], w1f[ks][n], acc1[n], 0, 0, 0);

        // ---- ReLU + stage h to per-wave LDS (swizzled) ----
        // C layout: col = n*16+q, row = g*4+r
#pragma unroll
        for (int n = 0; n < 8; ++n) {
#pragma unroll
            for (int r = 0; r < 4; ++r) {
                const int rr = g * 4 + r;
                const int c  = n * 16 + q;
                float hv = acc1[n][r];
                hv = hv > 0.0f ? hv : 0.0f;
                const int off = (rr * 128 + c) ^ ((rr & 7) << 3);
                hb[off] = f2bf(hv);
            }
        }

        // ---- read h A-fragments (same-wave LDS; compiler inserts lgkmcnt) ----
        short8 ha[4];
#pragma unroll
        for (int ks = 0; ks < 4; ++ks) {
            const int off = (q * 128 + ks * 32 + g * 8) ^ ((q & 7) << 3);
            ha[ks] = *(const short8*)&hb[off];
        }

        // ---- GEMM2: y[16][32] = relu(h) @ W2 + b2 ----
        f32x4 acc2[2];
#pragma unroll
        for (int n = 0; n < 2; ++n)
            acc2[n] = (f32x4){b2v[n], b2v[n], b2v[n], b2v[n]};
#pragma unroll
        for (int ks = 0; ks < 4; ++ks)
#pragma unroll
            for (int n = 0; n < 2; ++n)
                acc2[n] = __builtin_amdgcn_mfma_f32_16x16x32_bf16(ha[ks], w2f[ks][n], acc2[n], 0, 0, 0);

        // ---- store y: row = g*4+r, col = n*16+q ----
#pragma unroll
        for (int n = 0; n < 2; ++n)
#pragma unroll
            for (int r = 0; r < 4; ++r)
                y[(size_t)(row0 + g * 4 + r) * 32 + n * 16 + q] = acc2[n][r];
    }
}

extern "C" void kernel_launch(void* const* d_in, const int* in_sizes, int n_in,
                              void* d_out, int out_size, void* d_ws, size_t ws_size,
                              hipStream_t stream) {
    const float* x  = (const float*)d_in[0];
    const float* W1 = (const float*)d_in[1];
    const float* b1 = (const float*)d_in[2];
    const float* W2 = (const float*)d_in[3];
    const float* b2 = (const float*)d_in[4];
    float* y = (float*)d_out;

    const int blocks = 1024;  // 4 waves/block, 4 M-tiles per wave
    livenet_mlp<<<blocks, 256, 0, stream>>>(x, W1, b1, W2, b2, y);
}

// Round 2
// 24.733 us; speedup vs baseline: 1.0820x; 1.0820x over previous
//
#include <hip/hip_runtime.h>
#include <hip/hip_bf16.h>

// y = relu(x @ W1 + b1) @ W2 + b2
// x:[B,64] f32, W1:[64,128], b1:[128], W2:[128,32], b2:[32], y:[B,32] f32
#define B_ROWS 262144
#define N_TILES (B_ROWS / 16)

typedef short short8 __attribute__((ext_vector_type(8)));
typedef float f32x4 __attribute__((ext_vector_type(4)));

__device__ inline short f2bf(float f) {
    __hip_bfloat16 h = __float2bfloat16(f);
    return __builtin_bit_cast(short, h);
}

__global__ __launch_bounds__(256, 2) void livenet_mlp(
    const float* __restrict__ x, const float* __restrict__ W1,
    const float* __restrict__ b1, const float* __restrict__ W2,
    const float* __restrict__ b2, float* __restrict__ y) {
    // per-wave h staging buffer: 16 rows x 128 cols bf16 = 2048 shorts (4 KB)
    __shared__ short hbuf[4 * 2048];

    const int tid  = threadIdx.x;
    const int wid  = tid >> 6;
    const int lane = tid & 63;
    const int g    = lane >> 4;   // k-group 0..3
    const int q    = lane & 15;   // row/col within tile
    short* hb = hbuf + wid * 2048;

    // ---- load weight fragments once per wave (L2-resident, amortized) ----
    // GEMM1 B-frags: w1f[ks][n], element j = bf16(W1[(ks*32+g*8+j)*128 + n*16+q])
    short8 w1f[2][8];
#pragma unroll
    for (int ks = 0; ks < 2; ++ks)
#pragma unroll
        for (int n = 0; n < 8; ++n) {
            short8 v;
#pragma unroll
            for (int j = 0; j < 8; ++j)
                v[j] = f2bf(W1[(ks * 32 + g * 8 + j) * 128 + n * 16 + q]);
            w1f[ks][n] = v;
        }
    // GEMM2 B-frags: w2f[ks][n]
    short8 w2f[4][2];
#pragma unroll
    for (int ks = 0; ks < 4; ++ks)
#pragma unroll
        for (int n = 0; n < 2; ++n) {
            short8 v;
#pragma unroll
            for (int j = 0; j < 8; ++j)
                v[j] = f2bf(W2[(ks * 32 + g * 8 + j) * 32 + n * 16 + q]);
            w2f[ks][n] = v;
        }
    float b1v[8], b2v[2];
#pragma unroll
    for (int n = 0; n < 8; ++n) b1v[n] = b1[n * 16 + q];
#pragma unroll
    for (int n = 0; n < 2; ++n) b2v[n] = b2[n * 16 + q];

    const int gwave    = blockIdx.x * 4 + wid;
    const int n_gwaves = gridDim.x * 4;

    // ---- software pipeline: prefetch tile t+1 while computing tile t ----
    f32x4 cur[4], nxt[4];
    {
        const f32x4* p = (const f32x4*)(x + (size_t)(gwave * 16 + q) * 64 + g * 8);
        cur[0] = p[0];
        cur[1] = p[1];
        cur[2] = p[8];   // +32 floats
        cur[3] = p[9];
    }

    for (int tile = gwave; tile < N_TILES; tile += n_gwaves) {
        const int tn = tile + n_gwaves;
        if (tn < N_TILES) {
            const f32x4* p = (const f32x4*)(x + (size_t)(tn * 16 + q) * 64 + g * 8);
            nxt[0] = p[0];
            nxt[1] = p[1];
            nxt[2] = p[8];
            nxt[3] = p[9];
        }

        const int row0 = tile * 16;

        // ---- convert current tile to A-fragments (f32 -> bf16) ----
        short8 a[2];
#pragma unroll
        for (int ks = 0; ks < 2; ++ks) {
            f32x4 lo = cur[ks * 2 + 0];
            f32x4 hi = cur[ks * 2 + 1];
            short8 v;
            v[0] = f2bf(lo[0]); v[1] = f2bf(lo[1]); v[2] = f2bf(lo[2]); v[3] = f2bf(lo[3]);
            v[4] = f2bf(hi[0]); v[5] = f2bf(hi[1]); v[6] = f2bf(hi[2]); v[7] = f2bf(hi[3]);
            a[ks] = v;
        }

        // ---- GEMM1: h[16][128] = x @ W1 + b1 ----
        f32x4 acc1[8];
#pragma unroll
        for (int n = 0; n < 8; ++n)
            acc1[n] = (f32x4){b1v[n], b1v[n], b1v[n], b1v[n]};
#pragma unroll
        for (int ks = 0; ks < 2; ++ks)
#pragma unroll
            for (int n = 0; n < 8; ++n)
                acc1[n] = __builtin_amdgcn_mfma_f32_16x16x32_bf16(a[ks], w1f[ks][n], acc1[n], 0, 0, 0);

        // ---- ReLU + stage h to per-wave LDS (swizzled) ----
        // C layout: col = n*16+q, row = g*4+r
#pragma unroll
        for (int n = 0; n < 8; ++n) {
#pragma unroll
            for (int r = 0; r < 4; ++r) {
                const int rr = g * 4 + r;
                const int c  = n * 16 + q;
                float hv = acc1[n][r];
                hv = hv > 0.0f ? hv : 0.0f;
                const int off = (rr * 128 + c) ^ ((rr & 7) << 3);
                hb[off] = f2bf(hv);
            }
        }

        // ---- read h A-fragments (same-wave LDS; compiler inserts lgkmcnt) ----
        short8 ha[4];
#pragma unroll
        for (int ks = 0; ks < 4; ++ks) {
            const int off = (q * 128 + ks * 32 + g * 8) ^ ((q & 7) << 3);
            ha[ks] = *(const short8*)&hb[off];
        }

        // ---- GEMM2: y[16][32] = relu(h) @ W2 + b2 ----
        f32x4 acc2[2];
#pragma unroll
        for (int n = 0; n < 2; ++n)
            acc2[n] = (f32x4){b2v[n], b2v[n], b2v[n], b2v[n]};
#pragma unroll
        for (int ks = 0; ks < 4; ++ks)
#pragma unroll
            for (int n = 0; n < 2; ++n)
                acc2[n] = __builtin_amdgcn_mfma_f32_16x16x32_bf16(ha[ks], w2f[ks][n], acc2[n], 0, 0, 0);

        // ---- store y (nontemporal; write-once stream): row = g*4+r, col = n*16+q ----
#pragma unroll
        for (int n = 0; n < 2; ++n)
#pragma unroll
            for (int r = 0; r < 4; ++r)
                __builtin_nontemporal_store(
                    acc2[n][r], y + (size_t)(row0 + g * 4 + r) * 32 + n * 16 + q);

        // ---- rotate pipeline ----
        cur[0] = nxt[0]; cur[1] = nxt[1]; cur[2] = nxt[2]; cur[3] = nxt[3];
    }
}

extern "C" void kernel_launch(void* const* d_in, const int* in_sizes, int n_in,
                              void* d_out, int out_size, void* d_ws, size_t ws_size,
                              hipStream_t stream) {
    const float* x  = (const float*)d_in[0];
    const float* W1 = (const float*)d_in[1];
    const float* b1 = (const float*)d_in[2];
    const float* W2 = (const float*)d_in[3];
    const float* b2 = (const float*)d_in[4];
    float* y = (float*)d_out;

    // 512 blocks x 4 waves = 2048 waves, all resident (2 blocks/CU):
    // weight prologue + pipeline fill paid once per resident wave; 8 tiles/wave.
    const int blocks = 512;
    livenet_mlp<<<blocks, 256, 0, stream>>>(x, W1, b1, W2, b2, y);
}

// Round 4
// 24.027 us; speedup vs baseline: 1.1138x; 1.0294x over previous
//
#include <hip/hip_runtime.h>
#include <hip/hip_bf16.h>

// y = relu(x @ W1 + b1) @ W2 + b2
// x:[B,64] f32, W1:[64,128], b1:[128], W2:[128,32], b2:[32], y:[B,32] f32
//
// Transposed-output structure: GEMM1 computes h^T = W1^T x^T via mfma(w1f, a),
// so each lane holds row q (batch row) and 4 CONSECUTIVE h columns per acc reg.
// GEMM2 computes y^T = W2^T h^T, so y stores are two dwordx4 per lane.
#define B_ROWS 262144
#define N_TILES (B_ROWS / 16)

typedef short short8 __attribute__((ext_vector_type(8)));
typedef float f32x4 __attribute__((ext_vector_type(4)));

__device__ inline short f2bf(float f) {
    __hip_bfloat16 h = __float2bfloat16(f);
    return __builtin_bit_cast(short, h);
}
__device__ inline unsigned pk2(float a, float b) {
    unsigned lo = (unsigned short)f2bf(a);
    unsigned hi = (unsigned short)f2bf(b);
    return lo | (hi << 16);
}

__global__ __launch_bounds__(256, 2) void livenet_mlp(
    const float* __restrict__ x, const float* __restrict__ W1,
    const float* __restrict__ b1, const float* __restrict__ W2,
    const float* __restrict__ b2, float* __restrict__ y) {
    // per-wave h^T staging: 16 rows x 128 cols bf16 = 4 KB (colblock-swizzled)
    __shared__ __align__(16) short hbuf[4 * 2048];

    const int tid  = threadIdx.x;
    const int wid  = tid >> 6;
    const int lane = tid & 63;
    const int g    = lane >> 4;   // k-group 0..3
    const int q    = lane & 15;   // batch row within tile / col within frag
    short* hb = hbuf + wid * 2048;
    const int key = 2 * (q & 7);  // even XOR key: keeps b128 blocks contiguous

    // ---- weight fragments, loaded once per wave (L2-resident) ----
    // w1f[ks][n] lane(g,q) elem j = W1[32ks+8g+j][16n+q]  (= A-frag of W1^T tile)
    short8 w1f[2][8];
#pragma unroll
    for (int ks = 0; ks < 2; ++ks)
#pragma unroll
        for (int n = 0; n < 8; ++n) {
            short8 v;
#pragma unroll
            for (int j = 0; j < 8; ++j)
                v[j] = f2bf(W1[(ks * 32 + g * 8 + j) * 128 + n * 16 + q]);
            w1f[ks][n] = v;
        }
    // w2f[ks][n] lane(g,q) elem j = W2[32ks+8g+j][16n+q]
    short8 w2f[4][2];
#pragma unroll
    for (int ks = 0; ks < 4; ++ks)
#pragma unroll
        for (int n = 0; n < 2; ++n) {
            short8 v;
#pragma unroll
            for (int j = 0; j < 8; ++j)
                v[j] = f2bf(W2[(ks * 32 + g * 8 + j) * 32 + n * 16 + q]);
            w2f[ks][n] = v;
        }
    // bias as C-operand vectors: output row dim = mid/out index 16n+4g+r
    f32x4 binit1[8], binit2[2];
#pragma unroll
    for (int n = 0; n < 8; ++n)
        binit1[n] = *(const f32x4*)(b1 + n * 16 + 4 * g);
#pragma unroll
    for (int n = 0; n < 2; ++n)
        binit2[n] = *(const f32x4*)(b2 + n * 16 + 4 * g);

    const int gwave    = blockIdx.x * 4 + wid;
    const int n_gwaves = gridDim.x * 4;

    // ---- software pipeline: prefetch tile t+1 while computing tile t ----
    f32x4 cur[4], nxt[4];
    {
        const f32x4* p = (const f32x4*)(x + (size_t)(gwave * 16 + q) * 64 + g * 8);
        cur[0] = p[0]; cur[1] = p[1]; cur[2] = p[8]; cur[3] = p[9];
    }

    for (int tile = gwave; tile < N_TILES; tile += n_gwaves) {
        const int tn = tile + n_gwaves;
        if (tn < N_TILES) {
            const f32x4* p = (const f32x4*)(x + (size_t)(tn * 16 + q) * 64 + g * 8);
            nxt[0] = p[0]; nxt[1] = p[1]; nxt[2] = p[8]; nxt[3] = p[9];
        }

        const int row0 = tile * 16;

        // ---- x B-fragments: lane(g,q) elem j = x[row0+q][32ks+8g+j] ----
        short8 a[2];
#pragma unroll
        for (int ks = 0; ks < 2; ++ks) {
            f32x4 lo = cur[ks * 2 + 0];
            f32x4 hi = cur[ks * 2 + 1];
            short8 v;
            v[0] = f2bf(lo[0]); v[1] = f2bf(lo[1]); v[2] = f2bf(lo[2]); v[3] = f2bf(lo[3]);
            v[4] = f2bf(hi[0]); v[5] = f2bf(hi[1]); v[6] = f2bf(hi[2]); v[7] = f2bf(hi[3]);
            a[ks] = v;
        }

        // ---- GEMM1 (swapped): h^T tile n; lane(g,q) reg r = h[row0+q][16n+4g+r]
        f32x4 acc1[8];
#pragma unroll
        for (int n = 0; n < 8; ++n) {
            acc1[n] = __builtin_amdgcn_mfma_f32_16x16x32_bf16(w1f[0][n], a[0], binit1[n], 0, 0, 0);
            acc1[n] = __builtin_amdgcn_mfma_f32_16x16x32_bf16(w1f[1][n], a[1], acc1[n], 0, 0, 0);
        }

        // ---- ReLU + pack 4 consecutive cols -> one ds_write_b64 per n ----
        // colblock cb = 4n+g of row q, swizzled cb' = cb ^ key
#pragma unroll
        for (int n = 0; n < 8; ++n) {
            float h0 = fmaxf(acc1[n][0], 0.0f);
            float h1 = fmaxf(acc1[n][1], 0.0f);
            float h2 = fmaxf(acc1[n][2], 0.0f);
            float h3 = fmaxf(acc1[n][3], 0.0f);
            uint2 w;
            w.x = pk2(h0, h1);
            w.y = pk2(h2, h3);
            const int cbp = (4 * n + g) ^ key;
            ((uint2*)hb)[q * 32 + cbp] = w;
        }

        // ---- read h B-fragments: lane(g,q) elem j = h[row0+q][32ks+8g+j] ----
        short8 ha[4];
#pragma unroll
        for (int ks = 0; ks < 4; ++ks) {
            const int cbr = (8 * ks + 2 * g) ^ key;  // even -> 16B block intact
            ha[ks] = *(const short8*)&hb[q * 128 + 4 * cbr];
        }

        // ---- GEMM2 (swapped): y^T; lane(g,q) reg r = y[row0+q][16n+4g+r] ----
        f32x4 acc2[2];
#pragma unroll
        for (int n = 0; n < 2; ++n) {
            acc2[n] = __builtin_amdgcn_mfma_f32_16x16x32_bf16(w2f[0][n], ha[0], binit2[n], 0, 0, 0);
#pragma unroll
            for (int ks = 1; ks < 4; ++ks)
                acc2[n] = __builtin_amdgcn_mfma_f32_16x16x32_bf16(w2f[ks][n], ha[ks], acc2[n], 0, 0, 0);
        }

        // ---- store y: two dwordx4 per lane, fully coalesced ----
#pragma unroll
        for (int n = 0; n < 2; ++n)
            __builtin_nontemporal_store(
                acc2[n], (f32x4*)(y + (size_t)(row0 + q) * 32 + n * 16 + 4 * g));

        // ---- rotate pipeline ----
        cur[0] = nxt[0]; cur[1] = nxt[1]; cur[2] = nxt[2]; cur[3] = nxt[3];
    }
}

extern "C" void kernel_launch(void* const* d_in, const int* in_sizes, int n_in,
                              void* d_out, int out_size, void* d_ws, size_t ws_size,
                              hipStream_t stream) {
    const float* x  = (const float*)d_in[0];
    const float* W1 = (const float*)d_in[1];
    const float* b1 = (const float*)d_in[2];
    const float* W2 = (const float*)d_in[3];
    const float* b2 = (const float*)d_in[4];
    float* y = (float*)d_out;

    // 512 blocks x 4 waves = 2048 waves, all resident (2 blocks/CU); 8 tiles/wave.
    const int blocks = 512;
    livenet_mlp<<<blocks, 256, 0, stream>>>(x, W1, b1, W2, b2, y);
}